// Round 1
// baseline (205.496 us; speedup 1.0000x reference)
//
#include <hip/hip_runtime.h>
#include <hip/hip_bf16.h>

// Problem constants
#define B_ 8
#define C_ 64
#define N_ 4096
#define K_ 16
#define E_ 64
#define EPSBN 1e-5f
#define CNT1 524288.0f   // B*N*K
#define CNT3 32768.0f    // B*N

typedef short v8s __attribute__((ext_vector_type(8)));
typedef float v16f __attribute__((ext_vector_type(16)));

__device__ __forceinline__ unsigned short f2bf(float f) {
  union { float f; unsigned u; } v; v.f = f;
  unsigned u = v.u;
  u += 0x7fffu + ((u >> 16) & 1u);   // RNE
  return (unsigned short)(u >> 16);
}
__device__ __forceinline__ float bf2f(unsigned short s) {
  union { unsigned u; float f; } v; v.u = ((unsigned)s) << 16;
  return v.f;
}

// ---------------------------------------------------------------------------
// K0: transpose x (B,C,N)->xT (B,N,C) fp32, and cast W1/W2/W3 to bf16
// ---------------------------------------------------------------------------
__global__ void prep_kernel(const float* __restrict__ x,
                            const float* __restrict__ W1,
                            const float* __restrict__ W2,
                            const float* __restrict__ W3,
                            float* __restrict__ xT,
                            unsigned short* __restrict__ Wbf) {
  __shared__ float tile[64][65];
  int blk = blockIdx.x;
  int t = threadIdx.x;
  if (blk >= 512) {  // weight cast: 3*4096 elements
    int i = (blk - 512) * 256 + t;
    int w = i >> 12;
    const float* src = (w == 0) ? W1 : (w == 1) ? W2 : W3;
    Wbf[i] = f2bf(src[i & 4095]);
    return;
  }
  int b = blk >> 6;
  int n0 = (blk & 63) << 6;
  int tn = t & 63, cg = t >> 6;
  for (int i = 0; i < 16; ++i) {
    int c = cg * 16 + i;
    tile[c][tn] = x[(((size_t)(b * 64 + c)) << 12) + n0 + tn];
  }
  __syncthreads();
  int r = t >> 2, q = t & 3;
  float4* dst = (float4*)(xT + (((size_t)((b << 12) + n0 + r)) << 6) + q * 16);
  for (int ii = 0; ii < 4; ++ii) {
    float4 v;
    v.x = tile[q * 16 + ii * 4 + 0][r];
    v.y = tile[q * 16 + ii * 4 + 1][r];
    v.z = tile[q * 16 + ii * 4 + 2][r];
    v.w = tile[q * 16 + ii * 4 + 3][r];
    dst[ii] = v;
  }
}

// ---------------------------------------------------------------------------
// K1: gather + edge + GEMM1 (bf16 MFMA) -> h1 (bf16), stats1
// Tile = 64 points x 64 channels. 4 waves, each one 32x32 C-tile, K=64.
// LDS A-tile: 64 rows x 9 uint4 (72 bf16, padded) for bank spread.
// ---------------------------------------------------------------------------
__global__ __launch_bounds__(256, 2) void k1_gather_gemm(
    const float* __restrict__ xT, const int* __restrict__ idx,
    const unsigned short* __restrict__ Wb, unsigned short* __restrict__ h,
    float* __restrict__ stats) {
  __shared__ uint4 ldsA[64 * 9];
  __shared__ float bs[64], bq[64];
  int t = threadIdx.x;
  if (t < 64) { bs[t] = 0.f; bq[t] = 0.f; }
  int lane = t & 63, wid = t >> 6;
  int rb = wid & 1, ctile = wid >> 1;
  int l31 = lane & 31, lh = lane >> 5;
  int o = ctile * 32 + l31;
  v8s wf[4];
  for (int ks = 0; ks < 4; ++ks)
    wf[ks] = *((const v8s*)(Wb + o * 64 + ks * 16 + lh * 8));
  int r = t >> 2, q = t & 3;
  int arow = rb * 32 + l31;
  float ssum = 0.f, ssq = 0.f;
  for (int tile = blockIdx.x; tile < 8192; tile += gridDim.x) {
    int p0 = tile << 6;
    {  // stage edges
      int p = p0 + r;
      int s = p >> 4;
      int b = s >> 12;
      int j = idx[p];
      const float4* nb = (const float4*)(xT + (((size_t)((b << 12) + j)) << 6) + q * 16);
      const float4* ce = (const float4*)(xT + (((size_t)s) << 6) + q * 16);
      float e[16];
      for (int ii = 0; ii < 4; ++ii) {
        float4 a = nb[ii], c = ce[ii];
        e[ii * 4 + 0] = a.x - c.x; e[ii * 4 + 1] = a.y - c.y;
        e[ii * 4 + 2] = a.z - c.z; e[ii * 4 + 3] = a.w - c.w;
      }
      uint4 ch[2];
      unsigned* cu = (unsigned*)ch;
      for (int ii = 0; ii < 8; ++ii)
        cu[ii] = (unsigned)f2bf(e[ii * 2]) | ((unsigned)f2bf(e[ii * 2 + 1]) << 16);
      ldsA[r * 9 + q * 2 + 0] = ch[0];
      ldsA[r * 9 + q * 2 + 1] = ch[1];
    }
    __syncthreads();
    v16f acc;
    for (int i = 0; i < 16; ++i) acc[i] = 0.f;
    for (int ks = 0; ks < 4; ++ks) {
      v8s a = *((const v8s*)&ldsA[arow * 9 + ks * 2 + lh]);
      acc = __builtin_amdgcn_mfma_f32_32x32x16_bf16(a, wf[ks], acc, 0, 0, 0);
    }
    for (int i = 0; i < 16; ++i) {
      float v = acc[i];
      ssum += v; ssq += v * v;
      int row = (i & 3) + ((i >> 2) << 3) + (lh << 2);
      h[(((size_t)(p0 + rb * 32 + row)) << 6) + o] = f2bf(v);
    }
    __syncthreads();
  }
  ssum += __shfl_xor(ssum, 32);
  ssq += __shfl_xor(ssq, 32);
  if (lh == 0) { atomicAdd(&bs[o], ssum); atomicAdd(&bq[o], ssq); }
  __syncthreads();
  if (t < 64) atomicAdd(&stats[t], bs[t]);
  else if (t < 128) atomicAdd(&stats[t], bq[t - 64]);
}

// ---------------------------------------------------------------------------
// K2: BN1+ReLU fused, GEMM2 -> h2 (in-place over h1), stats2
// ---------------------------------------------------------------------------
__global__ __launch_bounds__(256, 2) void k2_bn_gemm(
    const unsigned short* __restrict__ Wb, unsigned short* __restrict__ h,
    const float* __restrict__ g1, const float* __restrict__ be1,
    float* __restrict__ stats) {
  __shared__ uint4 ldsA[64 * 9];
  __shared__ float bs[64], bq[64];
  __shared__ float lA[64], lC[64];
  int t = threadIdx.x;
  if (t < 64) {
    bs[t] = 0.f; bq[t] = 0.f;
    float mean = stats[t] / CNT1;
    float var = stats[64 + t] / CNT1 - mean * mean;
    float a = g1[t] * rsqrtf(var + EPSBN);
    lA[t] = a; lC[t] = be1[t] - mean * a;
  }
  __syncthreads();
  int lane = t & 63, wid = t >> 6;
  int rb = wid & 1, ctile = wid >> 1;
  int l31 = lane & 31, lh = lane >> 5;
  int o = ctile * 32 + l31;
  v8s wf[4];
  for (int ks = 0; ks < 4; ++ks)
    wf[ks] = *((const v8s*)(Wb + o * 64 + ks * 16 + lh * 8));
  int r = t >> 2, q = t & 3;
  int arow = rb * 32 + l31;
  float aa[16], cc[16];
  for (int i = 0; i < 16; ++i) { aa[i] = lA[q * 16 + i]; cc[i] = lC[q * 16 + i]; }
  float ssum = 0.f, ssq = 0.f;
  for (int tile = blockIdx.x; tile < 8192; tile += gridDim.x) {
    int p0 = tile << 6;
    {
      const uint4* hp = (const uint4*)(h + (((size_t)(p0 + r)) << 6)) + q * 2;
      uint4 u0 = hp[0], u1 = hp[1];
      const unsigned* uu0 = (const unsigned*)&u0;
      const unsigned* uu1 = (const unsigned*)&u1;
      uint4 chm[2]; unsigned* cm = (unsigned*)chm;
      for (int ii = 0; ii < 4; ++ii) {
        unsigned u = uu0[ii];
        float f0 = fmaxf(bf2f((unsigned short)(u & 0xffff)) * aa[2 * ii] + cc[2 * ii], 0.f);
        float f1 = fmaxf(bf2f((unsigned short)(u >> 16)) * aa[2 * ii + 1] + cc[2 * ii + 1], 0.f);
        cm[ii] = (unsigned)f2bf(f0) | ((unsigned)f2bf(f1) << 16);
        u = uu1[ii];
        f0 = fmaxf(bf2f((unsigned short)(u & 0xffff)) * aa[8 + 2 * ii] + cc[8 + 2 * ii], 0.f);
        f1 = fmaxf(bf2f((unsigned short)(u >> 16)) * aa[8 + 2 * ii + 1] + cc[8 + 2 * ii + 1], 0.f);
        cm[4 + ii] = (unsigned)f2bf(f0) | ((unsigned)f2bf(f1) << 16);
      }
      ldsA[r * 9 + q * 2 + 0] = chm[0];
      ldsA[r * 9 + q * 2 + 1] = chm[1];
    }
    __syncthreads();
    v16f acc;
    for (int i = 0; i < 16; ++i) acc[i] = 0.f;
    for (int ks = 0; ks < 4; ++ks) {
      v8s a = *((const v8s*)&ldsA[arow * 9 + ks * 2 + lh]);
      acc = __builtin_amdgcn_mfma_f32_32x32x16_bf16(a, wf[ks], acc, 0, 0, 0);
    }
    for (int i = 0; i < 16; ++i) {
      float v = acc[i];
      ssum += v; ssq += v * v;
      int row = (i & 3) + ((i >> 2) << 3) + (lh << 2);
      h[(((size_t)(p0 + rb * 32 + row)) << 6) + o] = f2bf(v);
    }
    __syncthreads();
  }
  ssum += __shfl_xor(ssum, 32);
  ssq += __shfl_xor(ssq, 32);
  if (lh == 0) { atomicAdd(&bs[o], ssum); atomicAdd(&bq[o], ssq); }
  __syncthreads();
  if (t < 64) atomicAdd(&stats[128 + t], bs[t]);
  else if (t < 128) atomicAdd(&stats[192 + (t - 64)], bq[t - 64]);
}

// ---------------------------------------------------------------------------
// K3: BN2+ReLU + max over K=16 neighbors, GEMM3 -> h3 (fp32), stats3
// Block = 64 sites (b,n). 512 blocks.
// ---------------------------------------------------------------------------
__global__ __launch_bounds__(256, 2) void k3_max_gemm(
    const unsigned short* __restrict__ Wb, const unsigned short* __restrict__ h,
    const float* __restrict__ g2, const float* __restrict__ be2,
    float* __restrict__ h3, float* __restrict__ stats) {
  __shared__ uint4 ldsA[64 * 9];
  __shared__ float bs[64], bq[64];
  __shared__ float lA[64], lC[64];
  int t = threadIdx.x;
  if (t < 64) {
    bs[t] = 0.f; bq[t] = 0.f;
    float mean = stats[128 + t] / CNT1;
    float var = stats[192 + t] / CNT1 - mean * mean;
    float a = g2[t] * rsqrtf(var + EPSBN);
    lA[t] = a; lC[t] = be2[t] - mean * a;
  }
  __syncthreads();
  int lane = t & 63, wid = t >> 6;
  int rb = wid & 1, ctile = wid >> 1;
  int l31 = lane & 31, lh = lane >> 5;
  int o = ctile * 32 + l31;
  v8s wf[4];
  for (int ks = 0; ks < 4; ++ks)
    wf[ks] = *((const v8s*)(Wb + o * 64 + ks * 16 + lh * 8));
  int r = t >> 2, q = t & 3;
  int arow = rb * 32 + l31;
  int s0 = blockIdx.x << 6;
  {
    int s = s0 + r;
    float aa[16], cc[16];
    for (int i = 0; i < 16; ++i) { aa[i] = lA[q * 16 + i]; cc[i] = lC[q * 16 + i]; }
    float mx[16];
    for (int i = 0; i < 16; ++i) mx[i] = 0.f;  // relu >= 0, safe identity
    for (int kk = 0; kk < 16; ++kk) {
      const uint4* hp = (const uint4*)(h + (((size_t)(s * 16 + kk)) << 6)) + q * 2;
      uint4 u0 = hp[0], u1 = hp[1];
      const unsigned* uu0 = (const unsigned*)&u0;
      const unsigned* uu1 = (const unsigned*)&u1;
      for (int ii = 0; ii < 4; ++ii) {
        unsigned u = uu0[ii];
        mx[2 * ii] = fmaxf(mx[2 * ii], bf2f((unsigned short)(u & 0xffff)) * aa[2 * ii] + cc[2 * ii]);
        mx[2 * ii + 1] = fmaxf(mx[2 * ii + 1], bf2f((unsigned short)(u >> 16)) * aa[2 * ii + 1] + cc[2 * ii + 1]);
        u = uu1[ii];
        mx[8 + 2 * ii] = fmaxf(mx[8 + 2 * ii], bf2f((unsigned short)(u & 0xffff)) * aa[8 + 2 * ii] + cc[8 + 2 * ii]);
        mx[8 + 2 * ii + 1] = fmaxf(mx[8 + 2 * ii + 1], bf2f((unsigned short)(u >> 16)) * aa[8 + 2 * ii + 1] + cc[8 + 2 * ii + 1]);
      }
    }
    uint4 ch[2]; unsigned* cu = (unsigned*)ch;
    for (int ii = 0; ii < 8; ++ii)
      cu[ii] = (unsigned)f2bf(mx[ii * 2]) | ((unsigned)f2bf(mx[ii * 2 + 1]) << 16);
    ldsA[r * 9 + q * 2 + 0] = ch[0];
    ldsA[r * 9 + q * 2 + 1] = ch[1];
  }
  __syncthreads();
  v16f acc;
  for (int i = 0; i < 16; ++i) acc[i] = 0.f;
  for (int ks = 0; ks < 4; ++ks) {
    v8s a = *((const v8s*)&ldsA[arow * 9 + ks * 2 + lh]);
    acc = __builtin_amdgcn_mfma_f32_32x32x16_bf16(a, wf[ks], acc, 0, 0, 0);
  }
  float ssum = 0.f, ssq = 0.f;
  for (int i = 0; i < 16; ++i) {
    float v = acc[i];
    ssum += v; ssq += v * v;
    int row = (i & 3) + ((i >> 2) << 3) + (lh << 2);
    h3[(((size_t)(s0 + rb * 32 + row)) << 6) + o] = v;
  }
  ssum += __shfl_xor(ssum, 32);
  ssq += __shfl_xor(ssq, 32);
  if (lh == 0) { atomicAdd(&bs[o], ssum); atomicAdd(&bq[o], ssq); }
  __syncthreads();
  if (t < 64) atomicAdd(&stats[256 + t], bs[t]);
  else if (t < 128) atomicAdd(&stats[320 + (t - 64)], bq[t - 64]);
}

// ---------------------------------------------------------------------------
// K4: BN3+ReLU, transpose (B,N,E)->(B,E,N), write out
// ---------------------------------------------------------------------------
__global__ void k4_out(const float* __restrict__ h3,
                       const float* __restrict__ g3, const float* __restrict__ be3,
                       float* __restrict__ out, const float* __restrict__ stats) {
  __shared__ float lA[64], lC[64];
  __shared__ float tile[64][65];
  int t = threadIdx.x;
  if (t < 64) {
    float mean = stats[256 + t] / CNT3;
    float var = stats[320 + t] / CNT3 - mean * mean;
    float a = g3[t] * rsqrtf(var + EPSBN);
    lA[t] = a; lC[t] = be3[t] - mean * a;
  }
  __syncthreads();
  int blk = blockIdx.x;
  int b = blk >> 6, n0 = (blk & 63) << 6;
  int r = t >> 2, q = t & 3;
  const float4* hp = (const float4*)(h3 + (((size_t)((b << 12) + n0 + r)) << 6)) + q * 4;
  for (int ii = 0; ii < 4; ++ii) {
    float4 v = hp[ii];
    int c = q * 16 + ii * 4;
    tile[c + 0][r] = fmaxf(v.x * lA[c + 0] + lC[c + 0], 0.f);
    tile[c + 1][r] = fmaxf(v.y * lA[c + 1] + lC[c + 1], 0.f);
    tile[c + 2][r] = fmaxf(v.z * lA[c + 2] + lC[c + 2], 0.f);
    tile[c + 3][r] = fmaxf(v.w * lA[c + 3] + lC[c + 3], 0.f);
  }
  __syncthreads();
  int oo = t >> 2, seg = t & 3;
  float4* dst = (float4*)(out + (((size_t)(b * 64 + oo)) << 12) + n0 + seg * 16);
  for (int ii = 0; ii < 4; ++ii) {
    float4 v;
    v.x = tile[oo][seg * 16 + ii * 4 + 0];
    v.y = tile[oo][seg * 16 + ii * 4 + 1];
    v.z = tile[oo][seg * 16 + ii * 4 + 2];
    v.w = tile[oo][seg * 16 + ii * 4 + 3];
    dst[ii] = v;
  }
}

// ---------------------------------------------------------------------------
extern "C" void kernel_launch(void* const* d_in, const int* in_sizes, int n_in,
                              void* d_out, int out_size, void* d_ws, size_t ws_size,
                              hipStream_t stream) {
  const float* x = (const float*)d_in[0];
  const int* idx = (const int*)d_in[1];
  const float* W1 = (const float*)d_in[2];
  const float* g1 = (const float*)d_in[4];
  const float* be1 = (const float*)d_in[5];
  const float* W2 = (const float*)d_in[6];
  const float* g2 = (const float*)d_in[8];
  const float* be2 = (const float*)d_in[9];
  const float* W3 = (const float*)d_in[10];
  const float* g3 = (const float*)d_in[12];
  const float* be3 = (const float*)d_in[13];
  float* out = (float*)d_out;

  char* ws = (char*)d_ws;
  float* xT = (float*)ws;                                     // 8 MB
  unsigned short* h = (unsigned short*)(ws + (8u << 20));     // 64 MB (h1, then h2 in-place)
  float* h3 = (float*)(ws + (72u << 20));                     // 8 MB
  unsigned short* Wbf = (unsigned short*)(ws + (80u << 20));  // 24 KB
  float* stats = (float*)(ws + (80u << 20) + (32u << 10));    // 384 floats

  hipMemsetAsync(stats, 0, 384 * sizeof(float), stream);
  prep_kernel<<<560, 256, 0, stream>>>(x, W1, W2, W3, xT, Wbf);
  k1_gather_gemm<<<1024, 256, 0, stream>>>(xT, idx, Wbf, h, stats);
  k2_bn_gemm<<<1024, 256, 0, stream>>>(Wbf + 4096, h, g1, be1, stats);
  k3_max_gemm<<<512, 256, 0, stream>>>(Wbf + 8192, h, g2, be2, h3, stats);
  k4_out<<<512, 256, 0, stream>>>(h3, g3, be3, out, stats);
}